// Round 15
// baseline (67.516 us; speedup 1.0000x reference)
//
#include <hip/hip_runtime.h>

// SigLoss: signature kernel PDE, loss = mean_a( K(X,X) + K(Y,Y) - 2 K(X,Y) ).
// A=256, L=256, D=32.
// R15: producer/consumer wave specialization. R14 proved one wave cannot
// overlap its own serial phases (in-order issue; 192-VGPR no pipelining
// headroom): MFMA phase (~700cyc) + scan chain (~1100cyc) simply add.
// Now 2 waves/problem: wave0 produces inc block b (MFMA, two-term f16 split)
// into incD[b&1]; wave1 scans block b-1 from incD[(b-1)&1] concurrently on a
// DIFFERENT SIMD. One barrier per block; parity double-buffer is race-free:
// producer passes barrier(b+1) (and may overwrite parity b) only after the
// consumer finished scan(b). Scan = R3-verified DPP core; reads/writes of
// inc keep R13's conflict-free 260-float row pitch.

typedef _Float16 half8 __attribute__((ext_vector_type(8)));
typedef float f32x4_t __attribute__((ext_vector_type(4)));
typedef unsigned int u32x4 __attribute__((ext_vector_type(4)));

#define DPP_ADD(v, ctrl, rmask)                                               \
    ((v) + __int_as_float(__builtin_amdgcn_update_dpp(                        \
               0, __float_as_int(v), (ctrl), (rmask), 0xF, true)))

#define INV2048 4.8828125e-4f

__global__ __launch_bounds__(128) void sig_pde(const float* __restrict__ X,
                                               const float* __restrict__ Y,
                                               float* __restrict__ partial) {
    const int bid = blockIdx.x;
    const int p = bid >> 8;          // 0=xx, 1=yy, 2=xy
    const int a = bid & 255;
    const float* __restrict__ U = (p == 1) ? Y : X;   // rows (i)
    const float* __restrict__ V = (p == 0) ? X : Y;   // cols (j)
    U += (size_t)a * 256 * 32;
    V += (size_t)a * 256 * 32;
    const int tid = threadIdx.x;
    const int wid = tid >> 6;            // 0 = producer, 1 = consumer
    const int lane = tid & 63;
    const int m16 = lane & 15;
    const int g2 = (lane >> 4) * 2;

    __shared__ __attribute__((aligned(16))) u32x4 bH[16 * 64];     // 16 KB
    __shared__ __attribute__((aligned(16))) u32x4 bL[16 * 64];     // 16 KB
    __shared__ __attribute__((aligned(16))) float incD[2][16 * 260]; // 33.3 KB

    const float4* U4 = (const float4*)U;
    const float4* V4 = (const float4*)V;

    // ---- Stage B fragments (split: wave w stages tiles w*8..w*8+7) ----
#pragma unroll 2
    for (int tt = 0; tt < 8; ++tt) {
        int t = wid * 8 + tt;
        int col = t * 16 + m16;
        int cp = (col + 1 < 256) ? col + 1 : 255;   // col 255 clamps -> dY=0
        float4 lo0 = V4[col * 8 + g2], lo1 = V4[col * 8 + g2 + 1];
        float4 hi0 = V4[cp * 8 + g2],  hi1 = V4[cp * 8 + g2 + 1];
        float d[8] = {hi0.x - lo0.x, hi0.y - lo0.y, hi0.z - lo0.z, hi0.w - lo0.w,
                      hi1.x - lo1.x, hi1.y - lo1.y, hi1.z - lo1.z, hi1.w - lo1.w};
        half8 bh, bl;
#pragma unroll
        for (int i = 0; i < 8; ++i) {
            _Float16 h = (_Float16)d[i];
            bh[i] = h;
            bl[i] = (_Float16)((d[i] - (float)h) * 2048.0f);
        }
        bH[t * 64 + lane] = __builtin_bit_cast(u32x4, bh);
        bL[t * 64 + lane] = __builtin_bit_cast(u32x4, bl);
    }
    __syncthreads();

    if (wid == 0) {
        // ================= PRODUCER =================
        auto loadA = [&](int blk, float4 (&dst)[4]) {
            int r0 = blk * 16 + m16;
            int r1 = (r0 + 1 < 256) ? r0 + 1 : 255;   // dX[255]:=0 (unscanned)
            dst[0] = U4[r0 * 8 + g2];
            dst[1] = U4[r0 * 8 + g2 + 1];
            dst[2] = U4[r1 * 8 + g2];
            dst[3] = U4[r1 * 8 + g2 + 1];
        };
        const f32x4_t zero4 = {0.0f, 0.0f, 0.0f, 0.0f};
        const f32x4_t mone4 = {-1.0f, -1.0f, -1.0f, -1.0f};
        const int rb = (lane >> 4) << 2;   // C rows g*4..g*4+3

        float4 A[4];
        loadA(0, A);
#pragma clang loop unroll(disable)
        for (int b = 0; b < 16; ++b) {
            // extract fragments, then immediately prefetch next A block
            float d[8] = {A[2].x - A[0].x, A[2].y - A[0].y,
                          A[2].z - A[0].z, A[2].w - A[0].w,
                          A[3].x - A[1].x, A[3].y - A[1].y,
                          A[3].z - A[1].z, A[3].w - A[1].w};
            half8 ah, al;
#pragma unroll
            for (int i = 0; i < 8; ++i) {
                _Float16 h = (_Float16)d[i];
                ah[i] = h;
                al[i] = (_Float16)((d[i] - (float)h) * 2048.0f);
            }
            if (b + 1 < 16) loadA(b + 1, A);   // hidden under MFMA phase
            float* __restrict__ inc = incD[b & 1];
#pragma unroll
            for (int t = 0; t < 16; ++t) {
                half8 bh = __builtin_bit_cast(half8, bH[t * 64 + lane]);
                half8 bl = __builtin_bit_cast(half8, bL[t * 64 + lane]);
                f32x4_t acc2 = __builtin_amdgcn_mfma_f32_16x16x32_f16(
                    ah, bl, zero4, 0, 0, 0);
                acc2 = __builtin_amdgcn_mfma_f32_16x16x32_f16(
                    al, bh, acc2, 0, 0, 0);
                f32x4_t acc1 = __builtin_amdgcn_mfma_f32_16x16x32_f16(
                    ah, bh, mone4, 0, 0, 0);
                int cc = t * 16 + m16;
                inc[(rb + 0) * 260 + cc] = fmaf(acc2[0], INV2048, acc1[0]);
                inc[(rb + 1) * 260 + cc] = fmaf(acc2[1], INV2048, acc1[1]);
                inc[(rb + 2) * 260 + cc] = fmaf(acc2[2], INV2048, acc1[2]);
                inc[(rb + 3) * 260 + cc] = fmaf(acc2[3], INV2048, acc1[3]);
            }
            __syncthreads();               // publish block b
        }
    } else {
        // ================= CONSUMER =================
        float kp0 = 1.0f, kp1 = 1.0f, kp2 = 1.0f, kp3 = 1.0f;

        auto scan_row = [&](float4 mv) {
            float kn = __int_as_float(__builtin_amdgcn_update_dpp(
                0, __float_as_int(kp0), 0x130 /*wave_shl:1*/, 0xF, 0xF, true));
            float c0 = fmaf(kp0, mv.x, kp1);
            float c1 = fmaf(kp1, mv.y, kp2);
            float c2 = fmaf(kp2, mv.z, kp3);
            float c3 = (lane == 63) ? 0.0f : fmaf(kp3, mv.w, kn);
            float L0 = c0, L1 = L0 + c1, L2 = L1 + c2;
            float T = L2 + c3;
            float S = T;
            S = DPP_ADD(S, 0x111, 0xF);  // row_shr:1
            S = DPP_ADD(S, 0x112, 0xF);  // row_shr:2
            S = DPP_ADD(S, 0x114, 0xF);  // row_shr:4
            S = DPP_ADD(S, 0x118, 0xF);  // row_shr:8
            S = DPP_ADD(S, 0x142, 0xA);  // row_bcast:15 -> rows 1,3
            S = DPP_ADD(S, 0x143, 0xC);  // row_bcast:31 -> rows 2,3
            float E = S - T;
            kp0 = 1.0f + E;
            kp1 = 1.0f + E + L0;
            kp2 = 1.0f + E + L1;
            kp3 = 1.0f + E + L2;
        };

#pragma clang loop unroll(disable)
        for (int b = 0; b < 16; ++b) {
            __syncthreads();               // wait for block b published
            const float4* rp = (const float4*)incD[b & 1];  // 65 f4 per row
            bool full = (b < 15);          // block 15: inc row 255 absent
            float4 ga0, ga1, ga2, ga3, gb0, gb1, gb2, gb3;
#define RD(Gv, r) Gv = rp[(r) * 65 + lane]
            RD(ga0, 0); RD(ga1, 1); RD(ga2, 2); RD(ga3, 3);
            RD(gb0, 4); RD(gb1, 5); RD(gb2, 6); RD(gb3, 7);
            scan_row(ga0); scan_row(ga1); scan_row(ga2); scan_row(ga3);
            RD(ga0, 8); RD(ga1, 9); RD(ga2, 10); RD(ga3, 11);
            scan_row(gb0); scan_row(gb1); scan_row(gb2); scan_row(gb3);
            RD(gb0, 12); RD(gb1, 13); RD(gb2, 14);
            if (full) RD(gb3, 15);
            scan_row(ga0); scan_row(ga1); scan_row(ga2); scan_row(ga3);
            scan_row(gb0); scan_row(gb1); scan_row(gb2);
            if (full) scan_row(gb3);
#undef RD
        }

        if (lane == 63) {
            // kp3 = K[255][255]
            partial[bid] = (p == 2 ? -2.0f : 1.0f) * kp3;
        }
    }
}

__global__ __launch_bounds__(256) void sig_reduce(const float* __restrict__ partial,
                                                  float* __restrict__ out) {
    const int t = threadIdx.x;
    float v = partial[t] + partial[t + 256] + partial[t + 512];
#pragma unroll
    for (int ofs = 32; ofs > 0; ofs >>= 1) v += __shfl_down(v, ofs);
    __shared__ float ws[4];
    if ((t & 63) == 0) ws[t >> 6] = v;
    __syncthreads();
    if (t == 0) out[0] = (ws[0] + ws[1] + ws[2] + ws[3]) * (1.0f / 256.0f);
}

extern "C" void kernel_launch(void* const* d_in, const int* in_sizes, int n_in,
                              void* d_out, int out_size, void* d_ws, size_t ws_size,
                              hipStream_t stream) {
    const float* X = (const float*)d_in[0];
    const float* Y = (const float*)d_in[1];
    float* partial = (float*)d_ws;       // 768 floats
    sig_pde<<<dim3(768), dim3(128), 0, stream>>>(X, Y, partial);
    sig_reduce<<<dim3(1), dim3(256), 0, stream>>>(partial, (float*)d_out);
}